// Round 12
// baseline (7640.439 us; speedup 1.0000x reference)
//
#include <hip/hip_runtime.h>
#include <math.h>

// ---- ws layout (bytes) ----
// contrib: [0, 51,773,440) as [v<5056][w*512+c] fp32; rows v>=5053 never read -> "hole"
//   hole @ 51,742,720: flags[2048] (+0), nUsed (+8192), list[2048] (+8448)
// feat: [51,773,440, +8,552,448)  (wT occupies its first 3 MB before convs)
// post-conv aliases inside contrib: WihT @0, preAll @2,097,152, hT/hB/hC/hD @19,202,048..,
//   WhhT @32,000,000 (524,288 B, ends 32,524,288 < hole)
#define HOLE_B 51742720ULL

// ---------------- init: zero output + dedup flags + doc feat row ----------------
__global__ __launch_bounds__(256) void k_init(unsigned int* __restrict__ out32, int n,
                                              unsigned int* __restrict__ hole32,
                                              float* __restrict__ featDoc){
  int t = blockIdx.x * 256 + threadIdx.x;
  if (t < n) out32[t] = 0u;
  if (t < 2112) hole32[t] = 0u;          // flags + nUsed (+pad)
  if (t < 512) featDoc[t] = 0.f;         // atomicMax target (relu floor 0)
}

// ---------------- mark used entities ----------------
__global__ __launch_bounds__(256) void k_mark(const int* __restrict__ cand, int* __restrict__ flags){
  int t = blockIdx.x * 256 + threadIdx.x;     // 2048 threads
  flags[cand[t]] = 1;
}

// ---------------- compact used entities into list ----------------
__global__ __launch_bounds__(256) void k_compact(const int* __restrict__ flags,
                                                 int* __restrict__ nUsed, int* __restrict__ list){
  int t = blockIdx.x * 256 + threadIdx.x;     // 2048 threads
  if (flags[t]){
    int s = atomicAdd(nUsed, 1);
    list[s] = t;
  }
}

// ---------------- repack conv_w[c][e][w] -> wT[e][w*512+c] ----------------
__global__ __launch_bounds__(256) void k_wT(const float* __restrict__ convw, float* __restrict__ wT){
  int t = blockIdx.x * 256 + threadIdx.x;      // < 300*2560 = 768000
  int e = t / 2560, wc = t - e * 2560;
  int w = wc >> 9, c = wc & 511;
  wT[t] = convw[(c * 300 + e) * 5 + w];
}

// ---------------- contrib GEMM: 16 rows x 5 cols per thread, fp32 ----------------
__global__ __launch_bounds__(256) void k_contrib(const float* __restrict__ emb,
                                                 const float* __restrict__ wT,
                                                 float* __restrict__ contrib){
  __shared__ float aS[16][304];                // 19,456 B
  int tid = threadIdx.x;
  int v0 = blockIdx.x * 16;                    // 316 tiles -> v < 5056
  int cb = blockIdx.y * 1280 + tid;            // y in {0,1}; cols cb + j*256, j<5
  #pragma unroll
  for (int r = 0; r < 16; ++r){
    int v = v0 + r;
    for (int e = tid; e < 304; e += 256)
      aS[r][e] = (v < 5053 && e < 300) ? emb[(size_t)v * 300 + e] : 0.f;
  }
  __syncthreads();
  float acc[5][16];
  #pragma unroll
  for (int j = 0; j < 5; ++j)
    #pragma unroll
    for (int r = 0; r < 16; ++r) acc[j][r] = 0.f;
  for (int e = 0; e < 300; e += 4){
    float b0[5], b1[5], b2[5], b3[5];
    #pragma unroll
    for (int j = 0; j < 5; ++j){
      b0[j] = wT[(size_t)(e + 0) * 2560 + cb + j * 256];
      b1[j] = wT[(size_t)(e + 1) * 2560 + cb + j * 256];
      b2[j] = wT[(size_t)(e + 2) * 2560 + cb + j * 256];
      b3[j] = wT[(size_t)(e + 3) * 2560 + cb + j * 256];
    }
    #pragma unroll
    for (int r = 0; r < 16; ++r){
      float4 a = *(const float4*)&aS[r][e];
      #pragma unroll
      for (int j = 0; j < 5; ++j)
        acc[j][r] += a.x * b0[j] + a.y * b1[j] + a.z * b2[j] + a.w * b3[j];
    }
  }
  #pragma unroll
  for (int r = 0; r < 16; ++r){
    if (v0 + r < 5053){                        // never write the hole rows
      #pragma unroll
      for (int j = 0; j < 5; ++j)
        contrib[(size_t)(v0 + r) * 2560 + cb + j * 256] = acc[j][r];
    }
  }
}

// ---------------- char-CNN gather: one block per sequence; optional entity list ----------------
__global__ __launch_bounds__(256) void k_conv(const int* __restrict__ idx, int L,
                                              const float* __restrict__ contrib,
                                              const float* __restrict__ convb,
                                              float* __restrict__ featAll, int row0,
                                              const int* __restrict__ list,
                                              const int* __restrict__ nUsed){
  __shared__ int tok[128];
  __shared__ float4 red[256];
  int b = blockIdx.x, tid = threadIdx.x;
  int s = b;
  if (list){
    if (b >= *nUsed) return;
    s = list[b];
  }
  const int* row = idx + (size_t)s * L;
  for (int i = tid; i < L; i += 256) tok[i] = row[i];
  __syncthreads();
  int c4 = tid & 127;                 // channel quad -> 512 channels
  int ph = tid >> 7;                  // position-half 0/1
  float4 bias = *(const float4*)(convb + c4 * 4);
  float4 mx = {0.f, 0.f, 0.f, 0.f};   // relu floor folded into init
  int P = L - 4;
  int half = (P + 1) >> 1;
  int p = ph ? half : 0;
  int pe = ph ? P : half;
  for (; p + 1 < pe; p += 2){         // 2 positions/iter -> 10 loads in flight
    float4 a0 = bias, a1 = bias;
    #pragma unroll
    for (int w = 0; w < 5; ++w){
      float4 v0 = *(const float4*)(contrib + ((size_t)tok[p + w] * 5 + w) * 512 + c4 * 4);
      float4 v1 = *(const float4*)(contrib + ((size_t)tok[p + 1 + w] * 5 + w) * 512 + c4 * 4);
      a0.x += v0.x; a0.y += v0.y; a0.z += v0.z; a0.w += v0.w;
      a1.x += v1.x; a1.y += v1.y; a1.z += v1.z; a1.w += v1.w;
    }
    mx.x = fmaxf(mx.x, fmaxf(a0.x, a1.x)); mx.y = fmaxf(mx.y, fmaxf(a0.y, a1.y));
    mx.z = fmaxf(mx.z, fmaxf(a0.z, a1.z)); mx.w = fmaxf(mx.w, fmaxf(a0.w, a1.w));
  }
  if (p < pe){                        // odd tail
    float4 a0 = bias;
    #pragma unroll
    for (int w = 0; w < 5; ++w){
      float4 v0 = *(const float4*)(contrib + ((size_t)tok[p + w] * 5 + w) * 512 + c4 * 4);
      a0.x += v0.x; a0.y += v0.y; a0.z += v0.z; a0.w += v0.w;
    }
    mx.x = fmaxf(mx.x, a0.x); mx.y = fmaxf(mx.y, a0.y);
    mx.z = fmaxf(mx.z, a0.z); mx.w = fmaxf(mx.w, a0.w);
  }
  red[tid] = mx;
  __syncthreads();
  if (tid < 128){
    float4 a = red[tid], bb = red[tid + 128];
    a.x = fmaxf(a.x, bb.x); a.y = fmaxf(a.y, bb.y);
    a.z = fmaxf(a.z, bb.z); a.w = fmaxf(a.w, bb.w);
    *(float4*)(featAll + (size_t)(row0 + s) * 512 + c4 * 4) = a;
  }
}

// ---------------- doc conv: 32 blocks x 16 positions, atomicMax merge ----------------
__global__ __launch_bounds__(256) void k_conv_doc(const int* __restrict__ doc,
                                                  const float* __restrict__ contrib,
                                                  const float* __restrict__ convb,
                                                  float* __restrict__ featDoc){
  __shared__ int tok[512];
  __shared__ float4 red[256];
  int b = blockIdx.x, tid = threadIdx.x;
  for (int i = tid; i < 512; i += 256) tok[i] = doc[i];
  __syncthreads();
  int c4 = tid & 127, ph = tid >> 7;
  float4 bias = *(const float4*)(convb + c4 * 4);
  float4 mx = {0.f, 0.f, 0.f, 0.f};
  int p0 = b * 16, p1 = min(p0 + 16, 508);
  int n = p1 - p0, half = (n + 1) >> 1;
  int p = p0 + (ph ? half : 0);
  int pe = ph ? p1 : p0 + half;
  for (; p < pe; ++p){
    float4 a0 = bias;
    #pragma unroll
    for (int w = 0; w < 5; ++w){
      float4 v0 = *(const float4*)(contrib + ((size_t)tok[p + w] * 5 + w) * 512 + c4 * 4);
      a0.x += v0.x; a0.y += v0.y; a0.z += v0.z; a0.w += v0.w;
    }
    mx.x = fmaxf(mx.x, a0.x); mx.y = fmaxf(mx.y, a0.y);
    mx.z = fmaxf(mx.z, a0.z); mx.w = fmaxf(mx.w, a0.w);
  }
  red[tid] = mx;
  __syncthreads();
  if (tid < 128){
    float4 a = red[tid], bb = red[tid + 128];
    a.x = fmaxf(a.x, bb.x); a.y = fmaxf(a.y, bb.y);
    a.z = fmaxf(a.z, bb.z); a.w = fmaxf(a.w, bb.w);
    // values >= 0 -> IEEE order == int order
    atomicMax((int*)(featDoc + c4 * 4 + 0), __float_as_int(a.x));
    atomicMax((int*)(featDoc + c4 * 4 + 1), __float_as_int(a.y));
    atomicMax((int*)(featDoc + c4 * 4 + 2), __float_as_int(a.z));
    atomicMax((int*)(featDoc + c4 * 4 + 3), __float_as_int(a.w));
  }
}

// ---------------- repack Wih -> WihT[dir][k][col] ----------------
__global__ __launch_bounds__(256) void k_wihT(const float* __restrict__ Wf,
                                              const float* __restrict__ Wb,
                                              float* __restrict__ WihT){
  int t = blockIdx.x * 256 + threadIdx.x;      // < 2*512*512 = 524288
  int dir = t >> 18, r = t & 262143;
  int k = r >> 9, col = r & 511;
  WihT[t] = (dir ? Wb : Wf)[col * 512 + k];
}

// ---------------- repack Whh -> WhhT[dir][j][row] (for coalesced streaming) ----------------
__global__ __launch_bounds__(256) void k_whhT(const float* __restrict__ Wf,
                                              const float* __restrict__ Wb,
                                              float* __restrict__ WhhT){
  int t = blockIdx.x * 256 + threadIdx.x;      // < 2*128*512 = 131072
  int dir = t >> 16, r = t & 65535;
  int j = r >> 9, row = r & 511;
  WhhT[t] = (dir ? Wb : Wf)[row * 128 + j];
}

// ---------------- input projection (fp32, 16 rows x 2 cols): preAll[dir][row][col] ----------------
__global__ __launch_bounds__(256) void k_proj(const float* __restrict__ featAll,
                                              const float* __restrict__ WihT,
                                              const float* __restrict__ bihF, const float* __restrict__ bhhF,
                                              const float* __restrict__ bihB, const float* __restrict__ bhhB,
                                              float* __restrict__ preAll){
  __shared__ float aS[16][516];                // 33,024 B
  int tid = threadIdx.x;
  int v0 = blockIdx.x * 16;                    // 261 tiles -> rows < 4176
  int dir = blockIdx.z;
  int col0 = tid, col1 = tid + 256;
  #pragma unroll
  for (int r = 0; r < 16; ++r)
    for (int k = tid; k < 516; k += 256)
      aS[r][k] = (k < 512) ? featAll[(size_t)(v0 + r) * 512 + k] : 0.f;
  __syncthreads();
  const float* BT = WihT + (size_t)dir * 262144;
  float acc0[16], acc1[16];
  #pragma unroll
  for (int r = 0; r < 16; ++r){ acc0[r] = 0.f; acc1[r] = 0.f; }
  for (int k = 0; k < 512; k += 4){
    float b00 = BT[(size_t)(k + 0) * 512 + col0];
    float b01 = BT[(size_t)(k + 1) * 512 + col0];
    float b02 = BT[(size_t)(k + 2) * 512 + col0];
    float b03 = BT[(size_t)(k + 3) * 512 + col0];
    float b10 = BT[(size_t)(k + 0) * 512 + col1];
    float b11 = BT[(size_t)(k + 1) * 512 + col1];
    float b12 = BT[(size_t)(k + 2) * 512 + col1];
    float b13 = BT[(size_t)(k + 3) * 512 + col1];
    #pragma unroll
    for (int r = 0; r < 16; ++r){
      float4 a = *(const float4*)&aS[r][k];
      acc0[r] += a.x * b00 + a.y * b01 + a.z * b02 + a.w * b03;
      acc1[r] += a.x * b10 + a.y * b11 + a.z * b12 + a.w * b13;
    }
  }
  float bias0 = (dir ? bihB : bihF)[col0] + (dir ? bhhB : bhhF)[col0];
  float bias1 = (dir ? bihB : bihF)[col1] + (dir ? bhhB : bhhF)[col1];
  float* outp = preAll + (size_t)dir * 4176 * 512;
  #pragma unroll
  for (int r = 0; r < 16; ++r){
    outp[(size_t)(v0 + r) * 512 + col0] = acc0[r] + bias0;
    outp[(size_t)(v0 + r) * 512 + col1] = acc1[r] + bias1;
  }
}

// ---------------- LSTM recurrence (fp64), 4 CHAINS PER BLOCK:
// each thread reads WhhT[j*512+tid] once and applies it to 4 chains' h vectors ->
// per-step L2 weight traffic /4 (this was the bound in r10/r11: 256 KB/block/step).
// Registers: 8 fp64 partials + 4 fp64 cst + few w's ~ 70 VGPR -> no spill.
__global__ __launch_bounds__(512, 2) void k_recur4(const float* __restrict__ preAll,
                                                   const float* __restrict__ WhhT,
                                                   const int* __restrict__ cand,
                                                   double* __restrict__ hT, double* __restrict__ hB,
                                                   double* __restrict__ hC, double* __restrict__ hD){
  int g0 = blockIdx.x * 4, dir = blockIdx.y, tid = threadIdx.x;
  const float* WT = WhhT + (size_t)dir * 65536;   // [128][512]
  const float* pre = preAll + (size_t)dir * 4176 * 512;
  __shared__ double hs[4][128];
  __shared__ double tS[4][512];
  __shared__ int candL[4][32];
  int lstm[4], bb[4], val[4];
  double* hout[4];
  #pragma unroll
  for (int g = 0; g < 4; ++g){
    int cc = g0 + g;
    val[g] = (cc < 193);
    int l = (cc < 64) ? 0 : (cc < 128) ? 1 : (cc < 192) ? 2 : 3;
    int b = (l == 3) ? 0 : (cc - l * 64);
    lstm[g] = l; bb[g] = b;
    double* ho = (l == 0) ? hT + (size_t)b * 8192
               : (l == 1) ? hB + (size_t)b * 8192
               : (l == 2) ? hC + (size_t)b * 8192 : hD;
    hout[g] = ho + dir * 128;
  }
  if (tid < 128){ hs[0][tid] = 0.0; hs[1][tid] = 0.0; hs[2][tid] = 0.0; hs[3][tid] = 0.0; }
  if (tid < 128){
    int g = tid >> 5, j = tid & 31;
    if (val[g] && lstm[g] < 2) candL[g][j] = cand[bb[g] * 32 + j];
  }
  __syncthreads();
  double cst[4] = {0.0, 0.0, 0.0, 0.0};          // live in tid<128
  for (int s = 0; s < 32; ++s){
    int t = dir ? (31 - s) : s;
    float pv[4];
    #pragma unroll
    for (int g = 0; g < 4; ++g){
      int rowi;
      if (!val[g])             rowi = 4160;
      else if (lstm[g] == 0)   rowi = candL[g][t];
      else if (lstm[g] == 1)   rowi = 2048 + candL[g][t];
      else if (lstm[g] == 2)   rowi = 4096 + bb[g];
      else                     rowi = 4160;
      pv[g] = pre[(size_t)rowi * 512 + tid];
    }
    double a0[4] = {0,0,0,0}, a1[4] = {0,0,0,0};  // 2 independent fp64 chains per g
    #pragma unroll
    for (int j = 0; j < 128; j += 4){
      float w0 = WT[(j + 0) * 512 + tid];
      float w1 = WT[(j + 1) * 512 + tid];
      float w2 = WT[(j + 2) * 512 + tid];
      float w3 = WT[(j + 3) * 512 + tid];
      #pragma unroll
      for (int g = 0; g < 4; ++g){
        a0[g] += (double)w0 * hs[g][j + 0];
        a1[g] += (double)w1 * hs[g][j + 1];
        a0[g] += (double)w2 * hs[g][j + 2];
        a1[g] += (double)w3 * hs[g][j + 3];
      }
    }
    bool isG = ((tid >> 7) == 2);                // rows 0-127:i 128-255:f 256-383:g 384-511:o
    #pragma unroll
    for (int g = 0; g < 4; ++g){
      double gg = (double)pv[g] + a0[g] + a1[g];
      tS[g][tid] = isG ? tanh(gg) : 1.0 / (1.0 + exp(-gg));
    }
    __syncthreads();
    if (tid < 128){
      #pragma unroll
      for (int g = 0; g < 4; ++g){
        cst[g] = tS[g][tid + 128] * cst[g] + tS[g][tid] * tS[g][tid + 256];
        double h = tS[g][tid + 384] * tanh(cst[g]);
        hs[g][tid] = h;
        if (val[g]) hout[g][(size_t)t * 256 + tid] = h;
      }
    }
    __syncthreads();
  }
}

// ---------------- BiDAF attention + scoring + scatter (fp64): one block per mention ----------------
__global__ __launch_bounds__(256) void k_att(const double* __restrict__ hC,
                                             const double* __restrict__ hT,
                                             const double* __restrict__ hD,
                                             const double* __restrict__ hB,
                                             const float* __restrict__ wc_g, const float* __restrict__ bc_g,
                                             const float* __restrict__ wq_g, const float* __restrict__ bq_g,
                                             const float* __restrict__ wcq_g, const float* __restrict__ bcq_g,
                                             const float* __restrict__ wz_g, const float* __restrict__ bz_g,
                                             const float* __restrict__ wp1_g, const float* __restrict__ bp1_g,
                                             const float* __restrict__ wp2_g, const float* __restrict__ bp2_g,
                                             const int* __restrict__ cand,
                                             float* __restrict__ out){
  int b = blockIdx.x, tid = threadIdx.x;
  __shared__ double sD[32][33];
  __shared__ double tD[32][33];
  __shared__ double cwS[32], qwS[32], qzS[32], smaxS[32], bsmS[32];
  __shared__ double q2cS[256];
  __shared__ double p1S[32], p2S[32], scoreS[32], redS[3];
  double bsum = (double)bc_g[0] + (double)bq_g[0] + (double)bcq_g[0];
  double bzv = (double)bz_g[0];
  double pa = 0.0;
  for (int pass = 0; pass < 2; ++pass){
    const double* cp = pass ? hD : (hC + (size_t)b * 8192);
    const double* qp = (pass ? hB : hT) + (size_t)b * 8192;
    if (tid < 32){
      double a = 0;
      for (int d = 0; d < 256; ++d) a += cp[(size_t)tid * 256 + d] * (double)wc_g[d];
      cwS[tid] = a;
    } else if (tid < 64){
      int j = tid - 32; double a = 0;
      for (int d = 0; d < 256; ++d) a += qp[(size_t)j * 256 + d] * (double)wq_g[d];
      qwS[j] = a;
    } else if (tid < 96){
      int j = tid - 64; double a = 0;
      for (int d = 0; d < 256; ++d) a += qp[(size_t)j * 256 + d] * (double)wz_g[256 + d];
      qzS[j] = a;
    }
    {
      int i = tid >> 3, js = tid & 7;
      double sa[4] = {0,0,0,0}, ta[4] = {0,0,0,0};
      for (int d = 0; d < 256; ++d){
        double cd = cp[(size_t)i * 256 + d];
        double cw1 = cd * (double)wcq_g[d];
        double cw2 = cd * (double)wz_g[512 + d];
        #pragma unroll
        for (int m = 0; m < 4; ++m){
          double qv = qp[(size_t)(js + m * 8) * 256 + d];
          sa[m] += cw1 * qv;
          ta[m] += cw2 * qv;
        }
      }
      __syncthreads();
      #pragma unroll
      for (int m = 0; m < 4; ++m){
        int j = js + m * 8;
        sD[i][j] = sa[m] + cwS[i] + qwS[j] + bsum;
        tD[i][j] = ta[m];
      }
    }
    __syncthreads();
    if (tid < 32){
      int i = tid;
      double mx = sD[i][0];
      for (int j = 1; j < 32; ++j) mx = fmax(mx, sD[i][j]);
      smaxS[i] = mx;
      double sum = 0, acc = 0;
      for (int j = 0; j < 32; ++j){
        double e = exp(sD[i][j] - mx);
        sum += e;
        acc += e * (qzS[j] + tD[i][j]);
      }
      pa = acc / sum;
    }
    __syncthreads();
    if (tid == 0){
      double mx = smaxS[0];
      for (int i = 1; i < 32; ++i) mx = fmax(mx, smaxS[i]);
      double sum = 0, e_[32];
      for (int i = 0; i < 32; ++i){ e_[i] = exp(smaxS[i] - mx); sum += e_[i]; }
      double inv = 1.0 / sum;
      for (int i = 0; i < 32; ++i) bsmS[i] = e_[i] * inv;
    }
    __syncthreads();
    {
      double a = 0;
      for (int i = 0; i < 32; ++i) a += bsmS[i] * cp[(size_t)i * 256 + tid];
      q2cS[tid] = a;
    }
    __syncthreads();
    if (tid < 32){
      int i = tid; double t1 = 0, t4 = 0;
      for (int d = 0; d < 256; ++d){
        double cd = cp[(size_t)i * 256 + d];
        t1 += cd * (double)wz_g[d];
        t4 += cd * q2cS[d] * (double)wz_g[768 + d];
      }
      double pv = t1 + pa + t4 + bzv;
      if (pass) p2S[i] = pv; else p1S[i] = pv;
    }
    __syncthreads();
  }
  if (tid < 32)
    scoreS[tid] = (double)wp1_g[0] * p1S[tid] + (double)bp1_g[0]
                + (double)wp2_g[0] * p2S[tid] + (double)bp2_g[0];
  __syncthreads();
  if (tid == 0){
    double mx = scoreS[0];
    for (int i = 1; i < 32; ++i) mx = fmax(mx, scoreS[i]);
    double es = 0, rs = 0;
    for (int i = 0; i < 32; ++i){ es += exp(scoreS[i] - mx); rs += scoreS[i]; }
    redS[0] = mx; redS[1] = es; redS[2] = rs;
  }
  __syncthreads();
  if (tid < 32){
    int col = cand[b * 32 + tid];
    double sc = scoreS[tid];
    out[(size_t)b * 2048 + col] = (float)sc;
    out[131072 + (size_t)b * 2048 + col] = (float)(exp(sc - redS[0]) / redS[1]);
    out[262144 + (size_t)b * 2048 + col] = (float)(sc / redS[2]);
  }
}

// ---------------------------------------------------------------------------
extern "C" void kernel_launch(void* const* d_in, const int* in_sizes, int n_in,
                              void* d_out, int out_size, void* d_ws, size_t ws_size,
                              hipStream_t stream) {
  const int* title_v = (const int*)d_in[0];
  const int* body_v  = (const int*)d_in[1];
  const int* ctx_v   = (const int*)d_in[3];
  const int* doc_v   = (const int*)d_in[4];
  const int* cand    = (const int*)d_in[5];
  const float* emb   = (const float*)d_in[6];
  const float* convw = (const float*)d_in[7];
  const float* convb = (const float*)d_in[8];
  const float* WihF  = (const float*)d_in[9];
  const float* WhhF  = (const float*)d_in[10];
  const float* bihF  = (const float*)d_in[11];
  const float* bhhF  = (const float*)d_in[12];
  const float* WihB  = (const float*)d_in[13];
  const float* WhhB  = (const float*)d_in[14];
  const float* bihB  = (const float*)d_in[15];
  const float* bhhB  = (const float*)d_in[16];
  float* out = (float*)d_out;

  const size_t CONTRIB_B = (size_t)5056 * 2560 * 4;     // 51,773,440
  const size_t FEAT_B    = (size_t)4176 * 512 * 4;      //  8,552,448
  char* base = (char*)d_ws;
  if (ws_size < CONTRIB_B + FEAT_B) return;
  float* contrib = (float*)base;
  char* featBase = base + CONTRIB_B;
  float* wT   = (float*)featBase;                       // dead before feat writes
  float* feat = (float*)featBase;
  float* featDoc = feat + (size_t)4160 * 512;

  // dedup buffers in the contrib hole (rows v>=5053, never read/written)
  int* flags = (int*)(base + HOLE_B);
  int* nUsed = (int*)(base + HOLE_B + 8192);
  int* list  = (int*)(base + HOLE_B + 8448);

  // post-conv aliases inside contrib
  float*  WihT   = (float*)(base);                      //  2,097,152 B
  float*  preAll = (float*)(base + 2097152);            // 17,104,896 B -> ends 19,202,048
  double* hT     = (double*)(base + 19202048);
  double* hB     = (double*)(base + 23396352);
  double* hC     = (double*)(base + 27590656);
  double* hD     = (double*)(base + 31784960);          // ends 31,850,496
  float*  WhhT   = (float*)(base + 32000000);           // 524,288 B -> ends 32,524,288 < HOLE_B

  k_init<<<(out_size + 255) / 256, 256, 0, stream>>>((unsigned int*)out, out_size,
                                                     (unsigned int*)(base + HOLE_B), featDoc);
  k_mark<<<8, 256, 0, stream>>>(cand, flags);
  k_compact<<<8, 256, 0, stream>>>(flags, nUsed, list);
  k_wT<<<3000, 256, 0, stream>>>(convw, wT);
  k_contrib<<<dim3(316, 2), 256, 0, stream>>>(emb, wT, contrib);

  k_conv<<<2048, 256, 0, stream>>>(title_v, 32, contrib, convb, feat, 0, list, nUsed);
  k_conv<<<2048, 256, 0, stream>>>(body_v, 128, contrib, convb, feat, 2048, list, nUsed);
  k_conv<<<64, 256, 0, stream>>>(ctx_v, 128, contrib, convb, feat, 4096, (const int*)nullptr, (const int*)nullptr);
  k_conv_doc<<<32, 256, 0, stream>>>(doc_v, contrib, convb, featDoc);

  // repacks into the (now dead) contrib region
  k_wihT<<<2048, 256, 0, stream>>>(WihF, WihB, WihT);
  k_whhT<<<512, 256, 0, stream>>>(WhhF, WhhB, WhhT);
  k_proj<<<dim3(261, 1, 2), 256, 0, stream>>>(feat, WihT, bihF, bhhF, bihB, bhhB, preAll);
  k_recur4<<<dim3(49, 2), 512, 0, stream>>>(preAll, WhhT, cand, hT, hB, hC, hD);
  k_att<<<64, 256, 0, stream>>>(hC, hT, hD, hB,
                                (const float*)d_in[17], (const float*)d_in[18],
                                (const float*)d_in[19], (const float*)d_in[20],
                                (const float*)d_in[21], (const float*)d_in[22],
                                (const float*)d_in[23], (const float*)d_in[24],
                                (const float*)d_in[25], (const float*)d_in[26],
                                (const float*)d_in[27], (const float*)d_in[28],
                                cand, out);
}

// Round 13
// 1189.857 us; speedup vs baseline: 6.4213x; 6.4213x over previous
//
#include <hip/hip_runtime.h>
#include <math.h>

// ---- ws layout (bytes) ----
// contrib: [0, 51,773,440) as [v<5056][w*512+c] fp32; rows v>=5053 never read -> "hole"
//   hole @ 51,742,720: flags[2048] (+0), nUsed (+8192), list[2048] (+8448)
// feat: [51,773,440, +8,552,448)  (wT occupies its first 3 MB before convs)
// post-conv aliases inside contrib: WihT @0, preAll @2,097,152, hT/hB/hC/hD @19,202,048..
#define HOLE_B 51742720ULL

// ---------------- init: zero output + dedup flags + doc feat row ----------------
__global__ __launch_bounds__(256) void k_init(unsigned int* __restrict__ out32, int n,
                                              unsigned int* __restrict__ hole32,
                                              float* __restrict__ featDoc){
  int t = blockIdx.x * 256 + threadIdx.x;
  if (t < n) out32[t] = 0u;
  if (t < 2112) hole32[t] = 0u;          // flags + nUsed (+pad)
  if (t < 512) featDoc[t] = 0.f;         // atomicMax target (relu floor 0)
}

// ---------------- mark used entities ----------------
__global__ __launch_bounds__(256) void k_mark(const int* __restrict__ cand, int* __restrict__ flags){
  int t = blockIdx.x * 256 + threadIdx.x;     // 2048 threads
  flags[cand[t]] = 1;
}

// ---------------- compact used entities into list ----------------
__global__ __launch_bounds__(256) void k_compact(const int* __restrict__ flags,
                                                 int* __restrict__ nUsed, int* __restrict__ list){
  int t = blockIdx.x * 256 + threadIdx.x;     // 2048 threads
  if (flags[t]){
    int s = atomicAdd(nUsed, 1);
    list[s] = t;
  }
}

// ---------------- repack conv_w[c][e][w] -> wT[e][w*512+c] ----------------
__global__ __launch_bounds__(256) void k_wT(const float* __restrict__ convw, float* __restrict__ wT){
  int t = blockIdx.x * 256 + threadIdx.x;      // < 300*2560 = 768000
  int e = t / 2560, wc = t - e * 2560;
  int w = wc >> 9, c = wc & 511;
  wT[t] = convw[(c * 300 + e) * 5 + w];
}

// ---------------- contrib GEMM: 16 rows x 5 cols per thread, fp32 ----------------
__global__ __launch_bounds__(256) void k_contrib(const float* __restrict__ emb,
                                                 const float* __restrict__ wT,
                                                 float* __restrict__ contrib){
  __shared__ float aS[16][304];                // 19,456 B
  int tid = threadIdx.x;
  int v0 = blockIdx.x * 16;                    // 316 tiles -> v < 5056
  int cb = blockIdx.y * 1280 + tid;            // y in {0,1}; cols cb + j*256, j<5
  #pragma unroll
  for (int r = 0; r < 16; ++r){
    int v = v0 + r;
    for (int e = tid; e < 304; e += 256)
      aS[r][e] = (v < 5053 && e < 300) ? emb[(size_t)v * 300 + e] : 0.f;
  }
  __syncthreads();
  float acc[5][16];
  #pragma unroll
  for (int j = 0; j < 5; ++j)
    #pragma unroll
    for (int r = 0; r < 16; ++r) acc[j][r] = 0.f;
  for (int e = 0; e < 300; e += 4){
    float b0[5], b1[5], b2[5], b3[5];
    #pragma unroll
    for (int j = 0; j < 5; ++j){
      b0[j] = wT[(size_t)(e + 0) * 2560 + cb + j * 256];
      b1[j] = wT[(size_t)(e + 1) * 2560 + cb + j * 256];
      b2[j] = wT[(size_t)(e + 2) * 2560 + cb + j * 256];
      b3[j] = wT[(size_t)(e + 3) * 2560 + cb + j * 256];
    }
    #pragma unroll
    for (int r = 0; r < 16; ++r){
      float4 a = *(const float4*)&aS[r][e];
      #pragma unroll
      for (int j = 0; j < 5; ++j)
        acc[j][r] += a.x * b0[j] + a.y * b1[j] + a.z * b2[j] + a.w * b3[j];
    }
  }
  #pragma unroll
  for (int r = 0; r < 16; ++r){
    if (v0 + r < 5053){                        // never write the hole rows
      #pragma unroll
      for (int j = 0; j < 5; ++j)
        contrib[(size_t)(v0 + r) * 2560 + cb + j * 256] = acc[j][r];
    }
  }
}

// ---------------- char-CNN gather: one block per sequence; 4-position unroll (20 loads in flight) ----------------
__global__ __launch_bounds__(256) void k_conv(const int* __restrict__ idx, int L,
                                              const float* __restrict__ contrib,
                                              const float* __restrict__ convb,
                                              float* __restrict__ featAll, int row0,
                                              const int* __restrict__ list,
                                              const int* __restrict__ nUsed){
  __shared__ int tok[128];
  __shared__ float4 red[256];
  int b = blockIdx.x, tid = threadIdx.x;
  int s = b;
  if (list){
    if (b >= *nUsed) return;
    s = list[b];
  }
  const int* row = idx + (size_t)s * L;
  for (int i = tid; i < L; i += 256) tok[i] = row[i];
  __syncthreads();
  int c4 = tid & 127;                 // channel quad -> 512 channels
  int ph = tid >> 7;                  // position-half 0/1
  float4 bias = *(const float4*)(convb + c4 * 4);
  float4 mx = {0.f, 0.f, 0.f, 0.f};   // relu floor folded into init
  int P = L - 4;
  int half = (P + 1) >> 1;
  int p = ph ? half : 0;
  int pe = ph ? P : half;
  for (; p + 3 < pe; p += 4){         // 4 positions/iter -> 20 float4 loads in flight
    float4 a0 = bias, a1 = bias, a2 = bias, a3 = bias;
    #pragma unroll
    for (int w = 0; w < 5; ++w){
      const float* bp = contrib + (size_t)w * 512 + c4 * 4;
      float4 v0 = *(const float4*)(bp + (size_t)tok[p + w] * 2560);
      float4 v1 = *(const float4*)(bp + (size_t)tok[p + 1 + w] * 2560);
      float4 v2 = *(const float4*)(bp + (size_t)tok[p + 2 + w] * 2560);
      float4 v3 = *(const float4*)(bp + (size_t)tok[p + 3 + w] * 2560);
      a0.x += v0.x; a0.y += v0.y; a0.z += v0.z; a0.w += v0.w;
      a1.x += v1.x; a1.y += v1.y; a1.z += v1.z; a1.w += v1.w;
      a2.x += v2.x; a2.y += v2.y; a2.z += v2.z; a2.w += v2.w;
      a3.x += v3.x; a3.y += v3.y; a3.z += v3.z; a3.w += v3.w;
    }
    mx.x = fmaxf(mx.x, fmaxf(fmaxf(a0.x, a1.x), fmaxf(a2.x, a3.x)));
    mx.y = fmaxf(mx.y, fmaxf(fmaxf(a0.y, a1.y), fmaxf(a2.y, a3.y)));
    mx.z = fmaxf(mx.z, fmaxf(fmaxf(a0.z, a1.z), fmaxf(a2.z, a3.z)));
    mx.w = fmaxf(mx.w, fmaxf(fmaxf(a0.w, a1.w), fmaxf(a2.w, a3.w)));
  }
  for (; p < pe; ++p){                // tail
    float4 a0 = bias;
    #pragma unroll
    for (int w = 0; w < 5; ++w){
      float4 v0 = *(const float4*)(contrib + ((size_t)tok[p + w] * 5 + w) * 512 + c4 * 4);
      a0.x += v0.x; a0.y += v0.y; a0.z += v0.z; a0.w += v0.w;
    }
    mx.x = fmaxf(mx.x, a0.x); mx.y = fmaxf(mx.y, a0.y);
    mx.z = fmaxf(mx.z, a0.z); mx.w = fmaxf(mx.w, a0.w);
  }
  red[tid] = mx;
  __syncthreads();
  if (tid < 128){
    float4 a = red[tid], bb = red[tid + 128];
    a.x = fmaxf(a.x, bb.x); a.y = fmaxf(a.y, bb.y);
    a.z = fmaxf(a.z, bb.z); a.w = fmaxf(a.w, bb.w);
    *(float4*)(featAll + (size_t)(row0 + s) * 512 + c4 * 4) = a;
  }
}

// ---------------- doc conv: 32 blocks x 16 positions, atomicMax merge ----------------
__global__ __launch_bounds__(256) void k_conv_doc(const int* __restrict__ doc,
                                                  const float* __restrict__ contrib,
                                                  const float* __restrict__ convb,
                                                  float* __restrict__ featDoc){
  __shared__ int tok[512];
  __shared__ float4 red[256];
  int b = blockIdx.x, tid = threadIdx.x;
  for (int i = tid; i < 512; i += 256) tok[i] = doc[i];
  __syncthreads();
  int c4 = tid & 127, ph = tid >> 7;
  float4 bias = *(const float4*)(convb + c4 * 4);
  float4 mx = {0.f, 0.f, 0.f, 0.f};
  int p0 = b * 16, p1 = min(p0 + 16, 508);
  int n = p1 - p0, half = (n + 1) >> 1;
  int p = p0 + (ph ? half : 0);
  int pe = ph ? p1 : p0 + half;
  for (; p < pe; ++p){
    float4 a0 = bias;
    #pragma unroll
    for (int w = 0; w < 5; ++w){
      float4 v0 = *(const float4*)(contrib + ((size_t)tok[p + w] * 5 + w) * 512 + c4 * 4);
      a0.x += v0.x; a0.y += v0.y; a0.z += v0.z; a0.w += v0.w;
    }
    mx.x = fmaxf(mx.x, a0.x); mx.y = fmaxf(mx.y, a0.y);
    mx.z = fmaxf(mx.z, a0.z); mx.w = fmaxf(mx.w, a0.w);
  }
  red[tid] = mx;
  __syncthreads();
  if (tid < 128){
    float4 a = red[tid], bb = red[tid + 128];
    a.x = fmaxf(a.x, bb.x); a.y = fmaxf(a.y, bb.y);
    a.z = fmaxf(a.z, bb.z); a.w = fmaxf(a.w, bb.w);
    // values >= 0 -> IEEE order == int order
    atomicMax((int*)(featDoc + c4 * 4 + 0), __float_as_int(a.x));
    atomicMax((int*)(featDoc + c4 * 4 + 1), __float_as_int(a.y));
    atomicMax((int*)(featDoc + c4 * 4 + 2), __float_as_int(a.z));
    atomicMax((int*)(featDoc + c4 * 4 + 3), __float_as_int(a.w));
  }
}

// ---------------- repack Wih -> WihT[dir][k][col] ----------------
__global__ __launch_bounds__(256) void k_wihT(const float* __restrict__ Wf,
                                              const float* __restrict__ Wb,
                                              float* __restrict__ WihT){
  int t = blockIdx.x * 256 + threadIdx.x;      // < 2*512*512 = 524288
  int dir = t >> 18, r = t & 262143;
  int k = r >> 9, col = r & 511;
  WihT[t] = (dir ? Wb : Wf)[col * 512 + k];
}

// ---------------- input projection (fp32, 16 rows x 2 cols): preAll[dir][row][col] ----------------
__global__ __launch_bounds__(256) void k_proj(const float* __restrict__ featAll,
                                              const float* __restrict__ WihT,
                                              const float* __restrict__ bihF, const float* __restrict__ bhhF,
                                              const float* __restrict__ bihB, const float* __restrict__ bhhB,
                                              float* __restrict__ preAll){
  __shared__ float aS[16][516];                // 33,024 B
  int tid = threadIdx.x;
  int v0 = blockIdx.x * 16;                    // 261 tiles -> rows < 4176
  int dir = blockIdx.z;
  int col0 = tid, col1 = tid + 256;
  #pragma unroll
  for (int r = 0; r < 16; ++r)
    for (int k = tid; k < 516; k += 256)
      aS[r][k] = (k < 512) ? featAll[(size_t)(v0 + r) * 512 + k] : 0.f;
  __syncthreads();
  const float* BT = WihT + (size_t)dir * 262144;
  float acc0[16], acc1[16];
  #pragma unroll
  for (int r = 0; r < 16; ++r){ acc0[r] = 0.f; acc1[r] = 0.f; }
  for (int k = 0; k < 512; k += 4){
    float b00 = BT[(size_t)(k + 0) * 512 + col0];
    float b01 = BT[(size_t)(k + 1) * 512 + col0];
    float b02 = BT[(size_t)(k + 2) * 512 + col0];
    float b03 = BT[(size_t)(k + 3) * 512 + col0];
    float b10 = BT[(size_t)(k + 0) * 512 + col1];
    float b11 = BT[(size_t)(k + 1) * 512 + col1];
    float b12 = BT[(size_t)(k + 2) * 512 + col1];
    float b13 = BT[(size_t)(k + 3) * 512 + col1];
    #pragma unroll
    for (int r = 0; r < 16; ++r){
      float4 a = *(const float4*)&aS[r][k];
      acc0[r] += a.x * b00 + a.y * b01 + a.z * b02 + a.w * b03;
      acc1[r] += a.x * b10 + a.y * b11 + a.z * b12 + a.w * b13;
    }
  }
  float bias0 = (dir ? bihB : bihF)[col0] + (dir ? bhhB : bhhF)[col0];
  float bias1 = (dir ? bihB : bihF)[col1] + (dir ? bhhB : bhhF)[col1];
  float* outp = preAll + (size_t)dir * 4176 * 512;
  #pragma unroll
  for (int r = 0; r < 16; ++r){
    outp[(size_t)(v0 + r) * 512 + col0] = acc0[r] + bias0;
    outp[(size_t)(v0 + r) * 512 + col1] = acc1[r] + bias1;
  }
}

// ---------------- LSTM recurrence (fp64): EXACT round-8 config — best measured (315 us).
// wr[128] register cache; compiler allocates 128 VGPR + one-time spill (~50 MB writes,
// not per-step reloads — FETCH stays ~23 MB). r9/r10/r12 alternatives all regressed.
__global__ __launch_bounds__(512) void k_recur(const float* __restrict__ preAll,
                                               const float* __restrict__ WhhF,
                                               const float* __restrict__ WhhB,
                                               const int* __restrict__ cand,
                                               double* __restrict__ hT, double* __restrict__ hB,
                                               double* __restrict__ hC, double* __restrict__ hD){
  int c = blockIdx.x, dir = blockIdx.y, tid = threadIdx.x;
  int lstm = (c < 64) ? 0 : (c < 128) ? 1 : (c < 192) ? 2 : 3;
  int b = (lstm == 3) ? 0 : (c - lstm * 64);
  const float* Whh = dir ? WhhB : WhhF;
  const float* pre = preAll + (size_t)dir * 4176 * 512;
  double* hout;
  if (lstm == 0)      hout = hT + (size_t)b * 32 * 256;
  else if (lstm == 1) hout = hB + (size_t)b * 32 * 256;
  else if (lstm == 2) hout = hC + (size_t)b * 32 * 256;
  else                hout = hD;
  hout += dir * 128;

  float wr[128];
  #pragma unroll
  for (int i = 0; i < 128; ++i) wr[i] = Whh[(size_t)tid * 128 + i];

  __shared__ double hs[128];
  __shared__ double gd[512];
  __shared__ int candL[32];
  if (tid < 128) hs[tid] = 0.0;
  if (lstm < 2 && tid < 32) candL[tid] = cand[b * 32 + tid];
  __syncthreads();
  double cst = 0.0;
  for (int s = 0; s < 32; ++s){
    int t = dir ? (31 - s) : s;
    int rowi;
    if (lstm == 0)      rowi = candL[t];
    else if (lstm == 1) rowi = 2048 + candL[t];
    else if (lstm == 2) rowi = 4096 + b;
    else                rowi = 4160;
    double g = (double)pre[(size_t)rowi * 512 + tid];
    #pragma unroll
    for (int j = 0; j < 128; ++j)
      g += (double)wr[j] * hs[j];
    gd[tid] = g;
    __syncthreads();
    if (tid < 128){
      double gi = gd[tid], gf = gd[tid + 128], gg = gd[tid + 256], go = gd[tid + 384];
      double si = 1.0 / (1.0 + exp(-gi));
      double sf = 1.0 / (1.0 + exp(-gf));
      double so = 1.0 / (1.0 + exp(-go));
      cst = sf * cst + si * tanh(gg);
      double h = so * tanh(cst);
      hs[tid] = h;
      hout[(size_t)t * 256 + tid] = h;
    }
    __syncthreads();
  }
}

// ---------------- BiDAF attention + scoring + scatter (fp64): one block per mention ----------------
__global__ __launch_bounds__(256) void k_att(const double* __restrict__ hC,
                                             const double* __restrict__ hT,
                                             const double* __restrict__ hD,
                                             const double* __restrict__ hB,
                                             const float* __restrict__ wc_g, const float* __restrict__ bc_g,
                                             const float* __restrict__ wq_g, const float* __restrict__ bq_g,
                                             const float* __restrict__ wcq_g, const float* __restrict__ bcq_g,
                                             const float* __restrict__ wz_g, const float* __restrict__ bz_g,
                                             const float* __restrict__ wp1_g, const float* __restrict__ bp1_g,
                                             const float* __restrict__ wp2_g, const float* __restrict__ bp2_g,
                                             const int* __restrict__ cand,
                                             float* __restrict__ out){
  int b = blockIdx.x, tid = threadIdx.x;
  __shared__ double sD[32][33];
  __shared__ double tD[32][33];
  __shared__ double cwS[32], qwS[32], qzS[32], smaxS[32], bsmS[32];
  __shared__ double q2cS[256];
  __shared__ double p1S[32], p2S[32], scoreS[32], redS[3];
  double bsum = (double)bc_g[0] + (double)bq_g[0] + (double)bcq_g[0];
  double bzv = (double)bz_g[0];
  double pa = 0.0;
  for (int pass = 0; pass < 2; ++pass){
    const double* cp = pass ? hD : (hC + (size_t)b * 8192);
    const double* qp = (pass ? hB : hT) + (size_t)b * 8192;
    if (tid < 32){
      double a = 0;
      for (int d = 0; d < 256; ++d) a += cp[(size_t)tid * 256 + d] * (double)wc_g[d];
      cwS[tid] = a;
    } else if (tid < 64){
      int j = tid - 32; double a = 0;
      for (int d = 0; d < 256; ++d) a += qp[(size_t)j * 256 + d] * (double)wq_g[d];
      qwS[j] = a;
    } else if (tid < 96){
      int j = tid - 64; double a = 0;
      for (int d = 0; d < 256; ++d) a += qp[(size_t)j * 256 + d] * (double)wz_g[256 + d];
      qzS[j] = a;
    }
    {
      int i = tid >> 3, js = tid & 7;
      double sa[4] = {0,0,0,0}, ta[4] = {0,0,0,0};
      for (int d = 0; d < 256; ++d){
        double cd = cp[(size_t)i * 256 + d];
        double cw1 = cd * (double)wcq_g[d];
        double cw2 = cd * (double)wz_g[512 + d];
        #pragma unroll
        for (int m = 0; m < 4; ++m){
          double qv = qp[(size_t)(js + m * 8) * 256 + d];
          sa[m] += cw1 * qv;
          ta[m] += cw2 * qv;
        }
      }
      __syncthreads();
      #pragma unroll
      for (int m = 0; m < 4; ++m){
        int j = js + m * 8;
        sD[i][j] = sa[m] + cwS[i] + qwS[j] + bsum;
        tD[i][j] = ta[m];
      }
    }
    __syncthreads();
    if (tid < 32){
      int i = tid;
      double mx = sD[i][0];
      for (int j = 1; j < 32; ++j) mx = fmax(mx, sD[i][j]);
      smaxS[i] = mx;
      double sum = 0, acc = 0;
      for (int j = 0; j < 32; ++j){
        double e = exp(sD[i][j] - mx);
        sum += e;
        acc += e * (qzS[j] + tD[i][j]);
      }
      pa = acc / sum;
    }
    __syncthreads();
    if (tid == 0){
      double mx = smaxS[0];
      for (int i = 1; i < 32; ++i) mx = fmax(mx, smaxS[i]);
      double sum = 0, e_[32];
      for (int i = 0; i < 32; ++i){ e_[i] = exp(smaxS[i] - mx); sum += e_[i]; }
      double inv = 1.0 / sum;
      for (int i = 0; i < 32; ++i) bsmS[i] = e_[i] * inv;
    }
    __syncthreads();
    {
      double a = 0;
      for (int i = 0; i < 32; ++i) a += bsmS[i] * cp[(size_t)i * 256 + tid];
      q2cS[tid] = a;
    }
    __syncthreads();
    if (tid < 32){
      int i = tid; double t1 = 0, t4 = 0;
      for (int d = 0; d < 256; ++d){
        double cd = cp[(size_t)i * 256 + d];
        t1 += cd * (double)wz_g[d];
        t4 += cd * q2cS[d] * (double)wz_g[768 + d];
      }
      double pv = t1 + pa + t4 + bzv;
      if (pass) p2S[i] = pv; else p1S[i] = pv;
    }
    __syncthreads();
  }
  if (tid < 32)
    scoreS[tid] = (double)wp1_g[0] * p1S[tid] + (double)bp1_g[0]
                + (double)wp2_g[0] * p2S[tid] + (double)bp2_g[0];
  __syncthreads();
  if (tid == 0){
    double mx = scoreS[0];
    for (int i = 1; i < 32; ++i) mx = fmax(mx, scoreS[i]);
    double es = 0, rs = 0;
    for (int i = 0; i < 32; ++i){ es += exp(scoreS[i] - mx); rs += scoreS[i]; }
    redS[0] = mx; redS[1] = es; redS[2] = rs;
  }
  __syncthreads();
  if (tid < 32){
    int col = cand[b * 32 + tid];
    double sc = scoreS[tid];
    out[(size_t)b * 2048 + col] = (float)sc;
    out[131072 + (size_t)b * 2048 + col] = (float)(exp(sc - redS[0]) / redS[1]);
    out[262144 + (size_t)b * 2048 + col] = (float)(sc / redS[2]);
  }
}

// ---------------------------------------------------------------------------
extern "C" void kernel_launch(void* const* d_in, const int* in_sizes, int n_in,
                              void* d_out, int out_size, void* d_ws, size_t ws_size,
                              hipStream_t stream) {
  const int* title_v = (const int*)d_in[0];
  const int* body_v  = (const int*)d_in[1];
  const int* ctx_v   = (const int*)d_in[3];
  const int* doc_v   = (const int*)d_in[4];
  const int* cand    = (const int*)d_in[5];
  const float* emb   = (const float*)d_in[6];
  const float* convw = (const float*)d_in[7];
  const float* convb = (const float*)d_in[8];
  const float* WihF  = (const float*)d_in[9];
  const float* WhhF  = (const float*)d_in[10];
  const float* bihF  = (const float*)d_in[11];
  const float* bhhF  = (const float*)d_in[12];
  const float* WihB  = (const float*)d_in[13];
  const float* WhhB  = (const float*)d_in[14];
  const float* bihB  = (const float*)d_in[15];
  const float* bhhB  = (const float*)d_in[16];
  float* out = (float*)d_out;

  const size_t CONTRIB_B = (size_t)5056 * 2560 * 4;     // 51,773,440
  const size_t FEAT_B    = (size_t)4176 * 512 * 4;      //  8,552,448
  char* base = (char*)d_ws;
  if (ws_size < CONTRIB_B + FEAT_B) return;
  float* contrib = (float*)base;
  char* featBase = base + CONTRIB_B;
  float* wT   = (float*)featBase;                       // dead before feat writes
  float* feat = (float*)featBase;
  float* featDoc = feat + (size_t)4160 * 512;

  // dedup buffers in the contrib hole (rows v>=5053, never read/written)
  int* flags = (int*)(base + HOLE_B);
  int* nUsed = (int*)(base + HOLE_B + 8192);
  int* list  = (int*)(base + HOLE_B + 8448);

  // post-conv aliases inside contrib
  float*  WihT   = (float*)(base);                      //  2,097,152 B
  float*  preAll = (float*)(base + 2097152);            // 17,104,896 B -> ends 19,202,048
  double* hT     = (double*)(base + 19202048);
  double* hB     = (double*)(base + 23396352);
  double* hC     = (double*)(base + 27590656);
  double* hD     = (double*)(base + 31784960);          // ends 31,850,496 < HOLE_B

  k_init<<<(out_size + 255) / 256, 256, 0, stream>>>((unsigned int*)out, out_size,
                                                     (unsigned int*)(base + HOLE_B), featDoc);
  k_mark<<<8, 256, 0, stream>>>(cand, flags);
  k_compact<<<8, 256, 0, stream>>>(flags, nUsed, list);
  k_wT<<<3000, 256, 0, stream>>>(convw, wT);
  k_contrib<<<dim3(316, 2), 256, 0, stream>>>(emb, wT, contrib);

  k_conv<<<2048, 256, 0, stream>>>(title_v, 32, contrib, convb, feat, 0, list, nUsed);
  k_conv<<<2048, 256, 0, stream>>>(body_v, 128, contrib, convb, feat, 2048, list, nUsed);
  k_conv<<<64, 256, 0, stream>>>(ctx_v, 128, contrib, convb, feat, 4096, (const int*)nullptr, (const int*)nullptr);
  k_conv_doc<<<32, 256, 0, stream>>>(doc_v, contrib, convb, featDoc);

  k_wihT<<<2048, 256, 0, stream>>>(WihF, WihB, WihT);
  k_proj<<<dim3(261, 1, 2), 256, 0, stream>>>(feat, WihT, bihF, bhhF, bihB, bhhB, preAll);
  k_recur<<<dim3(193, 2), 512, 0, stream>>>(preAll, WhhF, WhhB, cand, hT, hB, hC, hD);
  k_att<<<64, 256, 0, stream>>>(hC, hT, hD, hB,
                                (const float*)d_in[17], (const float*)d_in[18],
                                (const float*)d_in[19], (const float*)d_in[20],
                                (const float*)d_in[21], (const float*)d_in[22],
                                (const float*)d_in[23], (const float*)d_in[24],
                                (const float*)d_in[25], (const float*)d_in[26],
                                (const float*)d_in[27], (const float*)d_in[28],
                                cand, out);
}